// Round 9
// baseline (100.360 us; speedup 1.0000x reference)
//
#include <hip/hip_runtime.h>

typedef float f32x4 __attribute__((ext_vector_type(4)));
typedef float f32x16 __attribute__((ext_vector_type(16)));
typedef short s16x8 __attribute__((ext_vector_type(8)));
typedef short s16x4 __attribute__((ext_vector_type(4)));
typedef unsigned short u16;

#define NB 8
#define NC 64
#define NN 4096

// float -> bf16 bits, round-to-nearest-even
__device__ __forceinline__ u16 f2bf_rne(float f) {
    unsigned u = __float_as_uint(f);
    u += 0x7FFFu + ((u >> 16) & 1u);
    return (u16)(u >> 16);
}
__device__ __forceinline__ float bf2f(u16 v) {
    return __uint_as_float(((unsigned)v) << 16);
}
// pack two f32 -> one u32 of 2 bf16 (RNE), lo = first arg
__device__ __forceinline__ unsigned cvt_pk_bf16(float lo, float hi) {
    unsigned r;
    asm("v_cvt_pk_bf16_f32 %0, %1, %2" : "=v"(r) : "v"(lo), "v"(hi));
    return r;
}
// swap: a' = {a.lanes0-31, b.lanes0-31}, b' = {a.lanes32-63, b.lanes32-63}
__device__ __forceinline__ void pl32_swap(unsigned &a, unsigned &b) {
    asm("v_permlane32_swap_b32 %0, %1" : "+v"(a), "+v"(b));
}
// 2^x via the hardware transcendental unit (v_exp_f32)
__device__ __forceinline__ float exp2_hw(float x) {
    return __builtin_amdgcn_exp2f(x);
}

#define Z16 ((f32x16){0.f,0.f,0.f,0.f,0.f,0.f,0.f,0.f,0.f,0.f,0.f,0.f,0.f,0.f,0.f,0.f})

// ---------------------------------------------------------------------------
// Kernel 1 (unchanged): W' = [Wh(64); Wf(8); Wg(8)] @ x[b] via MFMA.
// Wf pre-scaled by log2(e). Qw/Gw: [B][N][16] bf16, top 8 zeroed. H written
// in PV-B-fragment order (Hf). Grid (b, n-tile) -> batch b pinned to XCD b.
// ---------------------------------------------------------------------------
__global__ __launch_bounds__(256, 4)
void precompute_qgh(const float* __restrict__ x,
                    const float* __restrict__ Wf,
                    const float* __restrict__ Wg,
                    const float* __restrict__ Wh,
                    u16* __restrict__ Qw, u16* __restrict__ Gw,
                    u16* __restrict__ Hf)
{
    const int b  = blockIdx.x;           // b fastest -> XCD = b
    const int n0 = blockIdx.y * 64;
    const int t  = threadIdx.x;
    const int wave = t >> 6, lane = t & 63, col = lane & 15, quad = lane >> 4;
    const float* xb = x + (size_t)b * NC * NN;

    __shared__ __align__(16) u16 WL[80][72];
    __shared__ __align__(16) u16 XT[64][72];

    #pragma unroll
    for (int r5 = 0; r5 < 5; r5++) {
        int v = r5 * 256 + t;
        int m = v >> 4, ks = (v & 15) << 2;
        const float* src = (m < 64) ? (Wh + m * 64 + ks)
                         : (m < 72) ? (Wf + (m - 64) * 64 + ks)
                                    : (Wg + (m - 72) * 64 + ks);
        const float scl = (m >= 64 && m < 72) ? 1.44269504088896f : 1.0f;
        f32x4 wv = *(const f32x4*)src;
        *(unsigned*)&WL[m][ks]     = (unsigned)f2bf_rne(wv[0] * scl) | ((unsigned)f2bf_rne(wv[1] * scl) << 16);
        *(unsigned*)&WL[m][ks + 2] = (unsigned)f2bf_rne(wv[2] * scl) | ((unsigned)f2bf_rne(wv[3] * scl) << 16);
    }
    #pragma unroll
    for (int r4 = 0; r4 < 4; r4++) {
        int v = r4 * 256 + t;
        int c = v >> 4, ns = (v & 15) << 2;
        f32x4 xv = *(const f32x4*)(xb + (size_t)c * NN + n0 + ns);
        #pragma unroll
        for (int e = 0; e < 4; e++) XT[ns + e][c] = f2bf_rne(xv[e]);
    }
    __syncthreads();

    const int n = n0 + wave * 16 + col;
    s16x8 bfrag[2], afrag[5][2];
    #pragma unroll
    for (int s = 0; s < 2; s++)
        bfrag[s] = *(const s16x8*)&XT[wave * 16 + col][s * 32 + quad * 8];
    #pragma unroll
    for (int mt = 0; mt < 5; mt++)
        #pragma unroll
        for (int s = 0; s < 2; s++)
            afrag[mt][s] = *(const s16x8*)&WL[mt * 16 + col][s * 32 + quad * 8];

    f32x4 d[5];
    #pragma unroll
    for (int mt = 0; mt < 5; mt++) d[mt] = (f32x4){0.f, 0.f, 0.f, 0.f};
    #pragma unroll
    for (int s = 0; s < 2; s++)
        #pragma unroll
        for (int mt = 0; mt < 5; mt++)
            d[mt] = __builtin_amdgcn_mfma_f32_16x16x32_bf16(afrag[mt][s], bfrag[s], d[mt], 0, 0, 0);

    union { s16x4 v; u16 e[4]; } pk4;
    #pragma unroll
    for (int r = 0; r < 4; r++) pk4.e[r] = f2bf_rne(d[4][r]);
    u16* qgbase = (quad < 2 ? Qw : Gw) + ((size_t)b * NN + n) * 16;
    *(s16x4*)(qgbase + (quad & 1) * 4) = pk4.v;
    if ((quad & 1) == 0) {
        s16x8 z;
        #pragma unroll
        for (int qz = 0; qz < 8; qz++) ((u16*)&z)[qz] = 0;
        *(s16x8*)(qgbase + 8) = z;
    }

    __syncthreads();
    u16 (*Hl)[72] = WL;                    // reuse WL space
    #pragma unroll
    for (int mt = 0; mt < 4; mt++)
        #pragma unroll
        for (int r = 0; r < 4; r++)
            Hl[mt * 16 + quad * 4 + r][wave * 16 + col] = f2bf_rne(d[mt][r]);
    __syncthreads();

    u16* HfB = Hf + (size_t)b * NC * NN + (size_t)blockIdx.y * 4096;
    #pragma unroll
    for (int it = 0; it < 2; it++) {
        int u = it * 256 + t;
        int s_local = u >> 7, chalf = (u >> 6) & 1, l = u & 63;
        s16x8 vv = *(const s16x8*)&Hl[chalf * 32 + (l & 31)][s_local * 16 + (l >> 5) * 8];
        *(s16x8*)(HfB + (size_t)((s_local * 2 + chalf) * 512 + l * 8)) = vv;
    }
}

// ---------------------------------------------------------------------------
// Kernel 2 v9: fused flash attention, 128-i BLOCKS (8 waves, 512 thr).
// Grid (8, 32) = 1 block/CU, batch->XCD pinned. Wave w: j-quarter q=w>>1,
// i-sub s=w&1 (64 i = 2 Q-tiles). Halves per-XCD L2 traffic 40 -> 20 MB vs
// R8, AND the wave pair (2q, 2q+1) reads the identical V/G stream on the
// same CU -> L1 hits halve L2 requests again. Depth-2 register prefetch
// (covers ~900cyc HBM first-touch; fill thrashes caches), s_setprio around
// the compute cluster. Per-wave main-loop math identical to R8.
// Epilogue: per i-sub, 4 quarter-partials tree-combined via LDS slabs.
// ---------------------------------------------------------------------------
__global__ __launch_bounds__(512, 2)
void attention_fused(const u16* __restrict__ Qw, const u16* __restrict__ Gw,
                     const u16* __restrict__ Hf,
                     const float* __restrict__ x, const float* __restrict__ gamma,
                     float* __restrict__ out)
{
    const int b  = blockIdx.x;           // b fastest -> XCD = b
    const int i0 = blockIdx.y * 128;
    const int t  = threadIdx.x;
    const int wave = t >> 6, lane = t & 63, col = lane & 31, hi = lane >> 5;
    const int q = wave >> 1, sown = wave & 1;

    __shared__ __align__(16) float Slab[2][64][72];   // [stage][c][i-in-sub] 36.9KB
    __shared__ float Lsh[4][4][32];                   // [tile][quarter][i]
    __shared__ float Sc4[4][32];                      // [tile][i]

    const u16* Qb  = Qw + (size_t)b * NN * 16;
    const u16* Gb  = Gw + (size_t)b * NN * 16;
    const u16* Hfb = Hf + (size_t)b * NC * NN;
    const float g = gamma[0];

    const int ibase = i0 + sown * 64;
    s16x8 qf0 = *(const s16x8*)(Qb + (size_t)(ibase + col) * 16 + hi * 8);
    s16x8 qf1 = *(const s16x8*)(Qb + (size_t)(ibase + 32 + col) * 16 + hi * 8);

    f32x16 o00 = Z16, o01 = Z16, o10 = Z16, o11 = Z16;  // [tile][chalf]
    float ls0a = 0.f, ls0b = 0.f, ls1a = 0.f, ls1b = 0.f;

    const int jbase = q * 1024;
    const u16* pvb = Hfb + (size_t)(jbase >> 4) * 1024 + (size_t)lane * 8;
    const u16* gb0 = Gb + (size_t)(jbase + col) * 16 + hi * 8;

    // chunk c: G frag at gb0 + c*512 (u16), V frags at pvb + c*2048 (u16).
    // overreads for c in {32,33} land in the adjacent ws regions (benign:
    // ws layout Hf -> Gw -> Qw).
#define LOADC(GA,V0,V1,V2,V3,c) do {                                  \
    GA = *(const s16x8*)(gb0 + (size_t)(c) * 512);                    \
    const u16* _p = pvb + (size_t)(c) * 2048;                         \
    V0 = *(const s16x8*)(_p);                                         \
    V1 = *(const s16x8*)(_p + 512);                                   \
    V2 = *(const s16x8*)(_p + 1024);                                  \
    V3 = *(const s16x8*)(_p + 1536); } while (0)

#define COMPUTEC(GA,V0,V1,V2,V3) do {                                               \
    __builtin_amdgcn_s_setprio(1);                                                  \
    f32x16 S0 = __builtin_amdgcn_mfma_f32_32x32x16_bf16(GA, qf0, Z16, 0, 0, 0);     \
    f32x16 S1 = __builtin_amdgcn_mfma_f32_32x32x16_bf16(GA, qf1, Z16, 0, 0, 0);     \
    _Pragma("unroll") for (int r = 0; r < 16; r++) S0[r] = exp2_hw(S0[r]);          \
    _Pragma("unroll") for (int r = 0; r < 16; r++) S1[r] = exp2_hw(S1[r]);          \
    _Pragma("unroll") for (int r = 0; r < 16; r += 2) {                             \
        ls0a += S0[r]; ls0b += S0[r + 1];                                           \
        ls1a += S1[r]; ls1b += S1[r + 1]; }                                         \
    _Pragma("unroll") for (int s2 = 0; s2 < 2; s2++) {                              \
        unsigned a0 = cvt_pk_bf16(S0[8*s2+0], S0[8*s2+1]);                          \
        unsigned a2 = cvt_pk_bf16(S0[8*s2+4], S0[8*s2+5]);                          \
        unsigned a1 = cvt_pk_bf16(S0[8*s2+2], S0[8*s2+3]);                          \
        unsigned a3 = cvt_pk_bf16(S0[8*s2+6], S0[8*s2+7]);                          \
        pl32_swap(a0, a2); pl32_swap(a1, a3);                                       \
        union { s16x8 v; unsigned u[4]; } p0;                                       \
        p0.u[0] = a0; p0.u[1] = a1; p0.u[2] = a2; p0.u[3] = a3;                     \
        unsigned b0 = cvt_pk_bf16(S1[8*s2+0], S1[8*s2+1]);                          \
        unsigned b2 = cvt_pk_bf16(S1[8*s2+4], S1[8*s2+5]);                          \
        unsigned b1 = cvt_pk_bf16(S1[8*s2+2], S1[8*s2+3]);                          \
        unsigned b3 = cvt_pk_bf16(S1[8*s2+6], S1[8*s2+7]);                          \
        pl32_swap(b0, b2); pl32_swap(b1, b3);                                       \
        union { s16x8 v; unsigned u[4]; } p1;                                       \
        p1.u[0] = b0; p1.u[1] = b1; p1.u[2] = b2; p1.u[3] = b3;                     \
        o00 = __builtin_amdgcn_mfma_f32_32x32x16_bf16(p0.v, s2 ? V2 : V0, o00, 0, 0, 0); \
        o01 = __builtin_amdgcn_mfma_f32_32x32x16_bf16(p0.v, s2 ? V3 : V1, o01, 0, 0, 0); \
        o10 = __builtin_amdgcn_mfma_f32_32x32x16_bf16(p1.v, s2 ? V2 : V0, o10, 0, 0, 0); \
        o11 = __builtin_amdgcn_mfma_f32_32x32x16_bf16(p1.v, s2 ? V3 : V1, o11, 0, 0, 0); \
    }                                                                               \
    __builtin_amdgcn_s_setprio(0); } while (0)

    s16x8 gA, vA0, vA1, vA2, vA3;
    s16x8 gB, vB0, vB1, vB2, vB3;
    s16x8 gC, vC0, vC1, vC2, vC3;
    LOADC(gA, vA0, vA1, vA2, vA3, 0);
    LOADC(gB, vB0, vB1, vB2, vB3, 1);

    for (int it = 0; it < 16; it++) {
        LOADC(gC, vC0, vC1, vC2, vC3, 2 * it + 2);
        COMPUTEC(gA, vA0, vA1, vA2, vA3);
        gA = gC; vA0 = vC0; vA1 = vC1; vA2 = vC2; vA3 = vC3;
        LOADC(gC, vC0, vC1, vC2, vC3, 2 * it + 3);
        COMPUTEC(gB, vB0, vB1, vB2, vB3);
        gB = gC; vB0 = vC0; vB1 = vC1; vB2 = vC2; vB3 = vC3;
    }

    float lsum0 = ls0a + ls0b;
    float lsum1 = ls1a + ls1b;
    // combine hi-halves (lane i and i+32 hold disjoint j'-sets)
    {
        unsigned a = __float_as_uint(lsum0), c2 = a;
        pl32_swap(a, c2);
        lsum0 = __uint_as_float(a) + __uint_as_float(c2);
        unsigned d = __float_as_uint(lsum1), e2 = d;
        pl32_swap(d, e2);
        lsum1 = __uint_as_float(d) + __uint_as_float(e2);
    }

    // publish per-tile l partials (tile T = sown*2 + k; lane col = i-in-tile)
    if (hi == 0) {
        Lsh[sown * 2 + 0][q][col] = lsum0;
        Lsh[sown * 2 + 1][q][col] = lsum1;
    }

    // ---- epilogue: per i-sub, tree-combine the 4 quarter partials ----
    // oacc layout: oKC[r] = O[c = C*32 + col][i-in-tile = ii(r,hi)]
#define II(r) (((r) & 3) + 8 * ((r) >> 2) + 4 * hi)
    #pragma unroll
    for (int s = 0; s < 2; s++) {
        const bool act = (sown == s);
        if (act && q == 1) {
            #pragma unroll
            for (int r = 0; r < 16; r++) {
                int ii = II(r);
                Slab[0][col][ii]           = o00[r];
                Slab[0][32 + col][ii]      = o01[r];
                Slab[0][col][32 + ii]      = o10[r];
                Slab[0][32 + col][32 + ii] = o11[r];
            }
        }
        if (act && q == 3) {
            #pragma unroll
            for (int r = 0; r < 16; r++) {
                int ii = II(r);
                Slab[1][col][ii]           = o00[r];
                Slab[1][32 + col][ii]      = o01[r];
                Slab[1][col][32 + ii]      = o10[r];
                Slab[1][32 + col][32 + ii] = o11[r];
            }
        }
        __syncthreads();
        if (s == 0 && wave == 0) {       // all Lsh visible after first sync
            #pragma unroll
            for (int T = 0; T < 4; T++)
                Sc4[T][col] = g / (Lsh[T][0][col] + Lsh[T][1][col] +
                                   Lsh[T][2][col] + Lsh[T][3][col]);
        }
        if (act && q == 0) {
            #pragma unroll
            for (int r = 0; r < 16; r++) {
                int ii = II(r);
                o00[r] += Slab[0][col][ii];
                o01[r] += Slab[0][32 + col][ii];
                o10[r] += Slab[0][col][32 + ii];
                o11[r] += Slab[0][32 + col][32 + ii];
            }
        }
        if (act && q == 2) {
            #pragma unroll
            for (int r = 0; r < 16; r++) {
                int ii = II(r);
                o00[r] += Slab[1][col][ii];
                o01[r] += Slab[1][32 + col][ii];
                o10[r] += Slab[1][col][32 + ii];
                o11[r] += Slab[1][32 + col][32 + ii];
            }
            #pragma unroll
            for (int r = 0; r < 16; r++) {
                int ii = II(r);
                Slab[1][col][ii]           = o00[r];
                Slab[1][32 + col][ii]      = o01[r];
                Slab[1][col][32 + ii]      = o10[r];
                Slab[1][32 + col][32 + ii] = o11[r];
            }
        }
        __syncthreads();
        if (act && q == 0) {
            #pragma unroll
            for (int r = 0; r < 16; r++) {
                int ii = II(r);
                Slab[0][col][ii]           = o00[r] + Slab[1][col][ii];
                Slab[0][32 + col][ii]      = o01[r] + Slab[1][32 + col][ii];
                Slab[0][col][32 + ii]      = o10[r] + Slab[1][col][32 + ii];
                Slab[0][32 + col][32 + ii] = o11[r] + Slab[1][32 + col][32 + ii];
            }
        }
        __syncthreads();
        // store i-sub s: 512 threads cover 64c x 64i
        {
            const int oc = t >> 3, q8 = t & 7;
            const int il = q8 * 8;                 // i within sub
            const int T  = s * 2 + (il >> 5);
            const int ii0 = il & 31;
            f32x4 sc0 = *(const f32x4*)&Sc4[T][ii0];
            f32x4 sc1 = *(const f32x4*)&Sc4[T][ii0 + 4];
            f32x4 o0 = *(const f32x4*)&Slab[0][oc][il];
            f32x4 o1 = *(const f32x4*)&Slab[0][oc][il + 4];
            const int gi = i0 + s * 64 + il;
            const float* xr = x   + ((size_t)b * NC + oc) * NN + gi;
            float*    orow  = out + ((size_t)b * NC + oc) * NN + gi;
            f32x4 x0 = *(const f32x4*)(xr);
            f32x4 x1 = *(const f32x4*)(xr + 4);
            f32x4 r0, r1;
            #pragma unroll
            for (int e = 0; e < 4; e++) {
                r0[e] = o0[e] * sc0[e] + x0[e];
                r1[e] = o1[e] * sc1[e] + x1[e];
            }
            *(f32x4*)(orow)     = r0;
            *(f32x4*)(orow + 4) = r1;
        }
        __syncthreads();                 // slabs free for next sub
    }
#undef II
#undef LOADC
#undef COMPUTEC
}

extern "C" void kernel_launch(void* const* d_in, const int* in_sizes, int n_in,
                              void* d_out, int out_size, void* d_ws, size_t ws_size,
                              hipStream_t stream) {
    const float* x     = (const float*)d_in[0];
    const float* Wf    = (const float*)d_in[1];
    const float* Wg    = (const float*)d_in[2];
    const float* Wh    = (const float*)d_in[3];
    const float* gamma = (const float*)d_in[4];
    float* out = (float*)d_out;

    // layout: Hf first, then Gw, then Qw — so last-iteration prefetch
    // overreads (Hf -> Gw, Gw -> Qw) stay inside the workspace.
    u16* Hf = (u16*)d_ws;                       // [B][256 slices][2][512] frag-order
    u16* Gw = Hf + (size_t)NB * NC * NN;        // [B][N][16] (top 8 zeroed)
    u16* Qw = Gw + (size_t)NB * NN * 16;        // [B][N][16] (top 8 zeroed)

    precompute_qgh<<<dim3(NB, 64), 256, 0, stream>>>(x, Wf, Wg, Wh, Qw, Gw, Hf);
    attention_fused<<<dim3(NB, 32), 512, 0, stream>>>(Qw, Gw, Hf, x, gamma, out);
}